// Round 1
// baseline (111.663 us; speedup 1.0000x reference)
//
#include <hip/hip_runtime.h>
#include <math.h>

#define BB 64          // batch
#define CC 16          // children per sample
#define DD 512         // feature dim
#define LL 8192        // CC*DD flattened length
#define EPSV 1e-8f
#define INVT 10.0f     // 1/TEMPERATURE

// ws layout (floats):
//  [0,     1024)  nrm2_i  : ||ci[b,c,:]||^2 for row r = b*16+c
//  [1024,  2048)  nrm2_j  : ||cj[b,c,:]||^2
//  [2048,  6144)  simj    : [64,64]
//  [6144, 10240)  simk    : [64,64]
//  [10240,10304)  posdot  : dot(fi, fj) per anchor
#define WS_N2I   0
#define WS_N2J   1024
#define WS_SIMJ  2048
#define WS_SIMK  6144
#define WS_POS   10240

// ---------------------------------------------------------------------------
// prep: blocks [0,1024): per-child squared norms, 2 rows per block.
//       blocks [1024,1088): positive-pair dot for anchor i = b-1024.
// ---------------------------------------------------------------------------
__global__ __launch_bounds__(256) void ntx_prep_kernel(const float* __restrict__ ci,
                                                       const float* __restrict__ cj,
                                                       float* __restrict__ ws) {
    const int b   = blockIdx.x;
    const int tid = threadIdx.x;
    __shared__ float red[4];

    if (b < 1024) {
        // two 512-float rows per block; threads 0-127 row0, 128-255 row1
        const bool is_j = (b >= 512);
        const int  bb   = is_j ? (b - 512) : b;
        const float* src = is_j ? cj : ci;
        const int row  = 2 * bb + (tid >> 7);       // global child-row index [0,1024)
        const int e4   = tid & 127;                 // float4 index within row (128 of them)
        float4 v = ((const float4*)(src + row * DD))[e4];
        float acc = v.x * v.x + v.y * v.y + v.z * v.z + v.w * v.w;
        #pragma unroll
        for (int off = 32; off; off >>= 1) acc += __shfl_down(acc, off);
        const int wave = tid >> 6, lane = tid & 63;
        if (lane == 0) red[wave] = acc;
        __syncthreads();
        if (tid == 0) {
            const int base = (is_j ? WS_N2J : WS_N2I) + 2 * bb;
            ws[base]     = red[0] + red[1];
            ws[base + 1] = red[2] + red[3];
        }
    } else {
        // positive dot: anchor i, 8192 floats = 2048 float4, 8 iters of 256
        const int i = b - 1024;
        const float4* fi = (const float4*)(ci + i * LL);
        const float4* fj = (const float4*)(cj + i * LL);
        float acc = 0.f;
        #pragma unroll
        for (int it = 0; it < 8; ++it) {
            const int l4 = tid + it * 256;
            float4 a = fi[l4], p = fj[l4];
            acc += a.x * p.x + a.y * p.y + a.z * p.z + a.w * p.w;
        }
        #pragma unroll
        for (int off = 32; off; off >>= 1) acc += __shfl_down(acc, off);
        const int wave = tid >> 6, lane = tid & 63;
        if (lane == 0) red[wave] = acc;
        __syncthreads();
        if (tid == 0) ws[WS_POS + i] = red[0] + red[1] + red[2] + red[3];
    }
}

// ---------------------------------------------------------------------------
// sim: one block per (i,j) pair. Gathered dot over L=8192 for both negatives.
// ---------------------------------------------------------------------------
__global__ __launch_bounds__(256) void ntx_sim_kernel(const float* __restrict__ ci,
                                                      const float* __restrict__ cj,
                                                      const int* __restrict__ nj,
                                                      const int* __restrict__ nk,
                                                      float* __restrict__ ws) {
    const int j = blockIdx.x;
    const int i = blockIdx.y;
    const int tid = threadIdx.x;

    __shared__ int   snj[CC], snk[CC];
    __shared__ float red[2][4];

    if (tid < CC)            snj[tid]      = nj[(i * BB + j) * CC + tid];
    else if (tid < 2 * CC)   snk[tid - CC] = nk[(i * BB + j) * CC + (tid - CC)];
    __syncthreads();

    const float4* fi = (const float4*)(ci + i * LL);
    float accj = 0.f, acck = 0.f;
    #pragma unroll
    for (int it = 0; it < 8; ++it) {
        const int l4 = tid + it * 256;      // float4 index in [0,2048)
        const int c  = l4 >> 7;             // child index (128 float4 per child)
        const int d4 = l4 & 127;
        float4 a  = fi[l4];
        float4 vj = ((const float4*)(cj + (j * CC + snj[c]) * DD))[d4];
        float4 vk = ((const float4*)(ci + (j * CC + snk[c]) * DD))[d4];
        accj += a.x * vj.x + a.y * vj.y + a.z * vj.z + a.w * vj.w;
        acck += a.x * vk.x + a.y * vk.y + a.z * vk.z + a.w * vk.w;
    }
    #pragma unroll
    for (int off = 32; off; off >>= 1) {
        accj += __shfl_down(accj, off);
        acck += __shfl_down(acck, off);
    }
    const int wave = tid >> 6, lane = tid & 63;
    if (lane == 0) { red[0][wave] = accj; red[1][wave] = acck; }
    __syncthreads();
    if (tid == 0) {
        const float sj = red[0][0] + red[0][1] + red[0][2] + red[0][3];
        const float sk = red[1][0] + red[1][1] + red[1][2] + red[1][3];
        const float* n2i = ws + WS_N2I;
        const float* n2j = ws + WS_N2J;
        float si = 0.f;
        #pragma unroll
        for (int c = 0; c < CC; ++c) si += n2i[i * CC + c];
        const float ni = fmaxf(sqrtf(si), EPSV);
        float gj = 0.f, gk = 0.f;
        #pragma unroll
        for (int c = 0; c < CC; ++c) {
            gj += n2j[j * CC + snj[c]];   // gathered negatives from cj
            gk += n2i[j * CC + snk[c]];   // gathered negatives from ci
        }
        ws[WS_SIMJ + i * BB + j] = sj / (ni * fmaxf(sqrtf(gj), EPSV));
        ws[WS_SIMK + i * BB + j] = sk / (ni * fmaxf(sqrtf(gk), EPSV));
    }
}

// ---------------------------------------------------------------------------
// final: 1 block, 64 lanes; lane i = anchor i: masked logsumexp over 129 logits.
// ---------------------------------------------------------------------------
__global__ __launch_bounds__(64) void ntx_final_kernel(const int* __restrict__ pids,
                                                       const float* __restrict__ ws,
                                                       float* __restrict__ out) {
    const int i = threadIdx.x;   // 0..63
    const float* n2i  = ws + WS_N2I;
    const float* n2j  = ws + WS_N2J;
    const float* simj = ws + WS_SIMJ;
    const float* simk = ws + WS_SIMK;
    const float* posd = ws + WS_POS;

    float si = 0.f, sjf = 0.f;
    #pragma unroll
    for (int c = 0; c < CC; ++c) { si += n2i[i * CC + c]; sjf += n2j[i * CC + c]; }
    const float ni  = fmaxf(sqrtf(si),  EPSV);
    const float njf = fmaxf(sqrtf(sjf), EPSV);
    const float l0  = posd[i] / (ni * njf) * INVT;

    const int mypid = pids[i];
    float m = l0;
    for (int jj = 0; jj < BB; ++jj) {
        if (jj != i && pids[jj] != mypid) {
            m = fmaxf(m, simj[i * BB + jj] * INVT);
            m = fmaxf(m, simk[i * BB + jj] * INVT);
        }
    }
    float s = expf(l0 - m);
    for (int jj = 0; jj < BB; ++jj) {
        if (jj != i && pids[jj] != mypid) {
            s += expf(simj[i * BB + jj] * INVT - m);
            s += expf(simk[i * BB + jj] * INVT - m);
        }
    }
    float loss = -l0 + m + logf(s);
    #pragma unroll
    for (int off = 32; off; off >>= 1) loss += __shfl_down(loss, off);
    if (i == 0) out[0] = loss / (2.0f * BB);
}

// ---------------------------------------------------------------------------
extern "C" void kernel_launch(void* const* d_in, const int* in_sizes, int n_in,
                              void* d_out, int out_size, void* d_ws, size_t ws_size,
                              hipStream_t stream) {
    const float* ci  = (const float*)d_in[0];   // children_is [64,16,512] f32
    const float* cj  = (const float*)d_in[1];   // children_js [64,16,512] f32
    const int*  pids = (const int*) d_in[2];    // partnet_ids [64] i32
    const int*  nj   = (const int*) d_in[3];    // neg_idx_j [64,64,16] i32
    const int*  nk   = (const int*) d_in[4];    // neg_idx_k [64,64,16] i32
    float* ws  = (float*)d_ws;
    float* out = (float*)d_out;

    ntx_prep_kernel<<<1088, 256, 0, stream>>>(ci, cj, ws);
    dim3 grid(BB, BB);
    ntx_sim_kernel<<<grid, 256, 0, stream>>>(ci, cj, nj, nk, ws);
    ntx_final_kernel<<<1, 64, 0, stream>>>(pids, ws, out);
}

// Round 2
// 79.838 us; speedup vs baseline: 1.3986x; 1.3986x over previous
//
#include <hip/hip_runtime.h>
#include <math.h>

#define BB 64          // batch
#define CC 16          // children per sample
#define DD 512         // feature dim
#define LL 8192        // CC*DD flattened length
#define EPSV 1e-8f
#define INVT 10.0f     // 1/TEMPERATURE
#define NEGINF_T (-1e31f)   // NEG_INF / TEMPERATURE

// ws layout (floats):
//  [0,     1024)  n2i : ||ci row r||^2   (r = b*16+c)
//  [1024,  2048)  n2j : ||cj row r||^2
//  [2048,  6144)  dj  : raw gathered dots vs cj  [64,64]
//  [6144, 10240)  dk  : raw gathered dots vs ci  [64,64]
//  [10240,10304)  pos : dot(fi, fj) per anchor
#define WS_N2I 0
#define WS_N2J 1024
#define WS_DJ  2048
#define WS_DK  6144
#define WS_POS 10240

__device__ __forceinline__ float dot4(float4 a, float4 b) {
    return a.x * b.x + a.y * b.y + a.z * b.z + a.w * b.w;
}

__device__ __forceinline__ float wave_reduce(float v) {
    #pragma unroll
    for (int off = 32; off; off >>= 1) v += __shfl_down(v, off);
    return v;
}

// ---------------------------------------------------------------------------
// prep: blocks [0,512): 4 child-row norms per block (1 wave = 1 row, no sync).
//       blocks [512,576): positive-pair dot for anchor i = b-512; b==512 also
//       zeroes out[0] (final kernel atomically accumulates into it).
// ---------------------------------------------------------------------------
__global__ __launch_bounds__(256) void ntx_prep(const float* __restrict__ ci,
                                                const float* __restrict__ cj,
                                                float* __restrict__ ws,
                                                float* __restrict__ out) {
    const int b = blockIdx.x, tid = threadIdx.x;
    __shared__ float red[4];
    if (b < 512) {
        const int row  = b * 4 + (tid >> 6);   // 0..2047 (first 1024 = ci rows)
        const int lane = tid & 63;
        const int r    = row & 1023;
        const float4* src = (const float4*)(row < 1024 ? ci : cj);
        float4 v1 = src[r * 128 + lane];
        float4 v2 = src[r * 128 + 64 + lane];
        float acc = dot4(v1, v1) + dot4(v2, v2);
        acc = wave_reduce(acc);
        if (lane == 0) ws[(row < 1024 ? WS_N2I : WS_N2J) + r] = acc;
    } else {
        const int i = b - 512;
        if (b == 512 && tid == 0) out[0] = 0.f;
        const float4* fi = (const float4*)(ci + i * LL);
        const float4* fj = (const float4*)(cj + i * LL);
        float acc = 0.f;
        #pragma unroll
        for (int it = 0; it < 8; ++it) acc += dot4(fi[tid + 256 * it], fj[tid + 256 * it]);
        acc = wave_reduce(acc);
        if ((tid & 63) == 0) red[tid >> 6] = acc;
        __syncthreads();
        if (tid == 0) ws[WS_POS + i] = red[0] + red[1] + red[2] + red[3];
    }
}

// ---------------------------------------------------------------------------
// sim: block (jt, i) computes raw gathered dots for j in [4*jt, 4*jt+4).
//      fi is register-cached (d4 = tid&127 is invariant per thread), so it is
//      loaded from global exactly once per block and reused for all 4 j's.
// ---------------------------------------------------------------------------
__global__ __launch_bounds__(256) void ntx_sim(const float* __restrict__ ci,
                                               const float* __restrict__ cj,
                                               const int* __restrict__ nj,
                                               const int* __restrict__ nk,
                                               float* __restrict__ ws) {
    const int jt  = blockIdx.x;   // 0..15
    const int i   = blockIdx.y;   // 0..63
    const int tid = threadIdx.x;

    __shared__ int   sidx[2][4][16];     // [side][jj][c]
    __shared__ float red[4][2][4];       // [jj][side][wave]

    if (tid < 64)        ((int*)sidx)[tid] = nj[i * 1024 + jt * 64 + tid];
    else if (tid < 128)  ((int*)sidx)[tid] = nk[i * 1024 + jt * 64 + (tid - 64)];

    const float4* fi4 = (const float4*)(ci + i * LL);
    float4 fiv[8];
    #pragma unroll
    for (int it = 0; it < 8; ++it) fiv[it] = fi4[tid + 256 * it];

    __syncthreads();

    const int d4   = tid & 127;   // float4 offset within a child row (invariant)
    const int half = tid >> 7;    // c parity handled by this half of the block
    const float4* cj4 = (const float4*)cj;
    const float4* ci4 = (const float4*)ci;

    #pragma unroll
    for (int jj = 0; jj < 4; ++jj) {
        const int j = jt * 4 + jj;
        const float4* bj = cj4 + j * CC * 128;
        const float4* bk = ci4 + j * CC * 128;
        float aj = 0.f, ak = 0.f;
        #pragma unroll
        for (int it = 0; it < 8; ++it) {
            const int c = half + 2 * it;           // (tid + it*256) >> 7
            float4 vj = bj[sidx[0][jj][c] * 128 + d4];
            float4 vk = bk[sidx[1][jj][c] * 128 + d4];
            aj += dot4(fiv[it], vj);
            ak += dot4(fiv[it], vk);
        }
        aj = wave_reduce(aj);
        ak = wave_reduce(ak);
        if ((tid & 63) == 0) { red[jj][0][tid >> 6] = aj; red[jj][1][tid >> 6] = ak; }
    }
    __syncthreads();
    if (tid < 8) {
        const int jj = tid >> 1, side = tid & 1;
        float s = red[jj][side][0] + red[jj][side][1] + red[jj][side][2] + red[jj][side][3];
        ws[(side ? WS_DK : WS_DJ) + i * BB + jt * 4 + jj] = s;
    }
}

// ---------------------------------------------------------------------------
// final: block i, lane j. Normalize raw dots, masked logsumexp over 129
// logits via wave butterfly, atomicAdd loss_i/(2B) into out.
// ---------------------------------------------------------------------------
__global__ __launch_bounds__(64) void ntx_final(const int* __restrict__ pids,
                                                const int* __restrict__ nj,
                                                const int* __restrict__ nk,
                                                const float* __restrict__ ws,
                                                float* __restrict__ out) {
    const int i = blockIdx.x, j = threadIdx.x;
    __shared__ float sn2i[1024], sn2j[1024];
    const float4* n2i4 = (const float4*)(ws + WS_N2I);
    const float4* n2j4 = (const float4*)(ws + WS_N2J);
    #pragma unroll
    for (int t = 0; t < 4; ++t) {
        ((float4*)sn2i)[j + 64 * t] = n2i4[j + 64 * t];
        ((float4*)sn2j)[j + 64 * t] = n2j4[j + 64 * t];
    }
    __syncthreads();

    float si = 0.f, sjf = 0.f;
    #pragma unroll
    for (int c = 0; c < CC; ++c) { si += sn2i[i * CC + c]; sjf += sn2j[i * CC + c]; }
    const float ni = fmaxf(sqrtf(si), EPSV);
    const float l0 = ws[WS_POS + i] / (ni * fmaxf(sqrtf(sjf), EPSV)) * INVT;

    float gj = 0.f, gk = 0.f;
    #pragma unroll
    for (int c = 0; c < CC; ++c) {
        gj += sn2j[j * CC + nj[(i * BB + j) * CC + c]];
        gk += sn2i[j * CC + nk[(i * BB + j) * CC + c]];
    }

    const bool valid = (j != i) && (pids[j] != pids[i]);
    float lj = NEGINF_T, lk = NEGINF_T;
    if (valid) {
        const float inv = INVT / ni;
        lj = ws[WS_DJ + i * BB + j] / fmaxf(sqrtf(gj), EPSV) * inv;
        lk = ws[WS_DK + i * BB + j] / fmaxf(sqrtf(gk), EPSV) * inv;
    }

    float m = fmaxf(lj, lk);
    #pragma unroll
    for (int off = 32; off; off >>= 1) m = fmaxf(m, __shfl_xor(m, off));
    m = fmaxf(m, l0);

    float s = __expf(lj - m) + __expf(lk - m);
    s = wave_reduce(s);
    if (j == 0) {
        s += __expf(l0 - m);
        const float loss_i = -l0 + m + __logf(s);
        atomicAdd(out, loss_i * (1.0f / (2.0f * BB)));
    }
}

// ---------------------------------------------------------------------------
extern "C" void kernel_launch(void* const* d_in, const int* in_sizes, int n_in,
                              void* d_out, int out_size, void* d_ws, size_t ws_size,
                              hipStream_t stream) {
    const float* ci  = (const float*)d_in[0];
    const float* cj  = (const float*)d_in[1];
    const int*  pids = (const int*) d_in[2];
    const int*  nj   = (const int*) d_in[3];
    const int*  nk   = (const int*) d_in[4];
    float* ws  = (float*)d_ws;
    float* out = (float*)d_out;

    ntx_prep<<<576, 256, 0, stream>>>(ci, cj, ws, out);
    ntx_sim<<<dim3(16, BB), 256, 0, stream>>>(ci, cj, nj, nk, ws);
    ntx_final<<<BB, 64, 0, stream>>>(pids, nj, nk, ws, out);
}